// Round 6
// baseline (519.061 us; speedup 1.0000x reference)
//
#include <hip/hip_runtime.h>
#include <hip/hip_bf16.h>

#define CUT 10
#define NB 256
#define NLAYERS 4
#define WSTRIDE 48

// real slot map (each real slot = 10x10 float, 100 floats)
#define R_DM 0        // 1024 input-displacement matrices (real)
#define R_SQ 1024     // 16 squeezers (l*4+m) (real)
#define R_DS 1040     // 16 displacement radial parts (l*4+m) (real)
#define R_BS 1056     // 48 gates * 19 photon-number blocks (real)
#define NRSLOTS 1968  // real slots; +1 extra build block for complex S0

// physical (bank-swizzled) per-mode strides: ph = 1110*n0 + 111*n1 + 11*n2 + n3
#define F0 1110
#define F1 111
#define F2 11
#define F3 1
#define ST_PHYS 11100

// rotation LUT layout (float2 entries = e^{i*ang})
#define LUT_A  0     // [6][10] e^{i f0_g * h}
#define LUT_B  60    // [6][10] e^{i f1_g * l}
#define LUT_C  120   // [6][19] e^{i (f3_g N + fdc_g lo(N))}
#define LUT_I  234   // [19]    e^{-i phi1 lo(N)}   (gate-0 input rot start)
#define LUT_S  253   // [6]     e^{i fdc_g}         (row step)
#define LUT_IS 259   // [1]     e^{-i phi1}         (input rot step)
#define LUT_K  260   // [4][10] e^{i (kap_m q^2 + phd_m q)}
#define LUT_N  300
#define LUT_PAD 320

typedef __hip_bfloat16 bf16;

// read element i of a buffer whose dtype (f32 vs bf16) was sniffed at runtime
__device__ __forceinline__ float readv(const void* p, int i, int isf32) {
  if (isf32) return ((const float*)p)[i];
  return __bfloat162float(((const bf16*)p)[i]);
}

// real MAC: acc += m * v (complex v, real m), m = mm.x (rmacL) or mm.y (rmacH)
// -> ONE v_pk_fma_f32 per complex MAC (the real-algebra payoff)
__device__ __forceinline__ void rmacL(float2& a, float2 mm, float2 v) {
  asm("v_pk_fma_f32 %0, %1, %2, %0 op_sel:[0,0,0] op_sel_hi:[0,1,1]"
      : "+v"(a) : "v"(mm), "v"(v));
}
__device__ __forceinline__ void rmacH(float2& a, float2 mm, float2 v) {
  asm("v_pk_fma_f32 %0, %1, %2, %0 op_sel:[1,0,0] op_sel_hi:[1,1,1]"
      : "+v"(a) : "v"(mm), "v"(v));
}

// full complex multiply d = u*v : 2 packed ops
__device__ __forceinline__ float2 cmul(float2 u, float2 v) {
  float2 d;
  asm("v_pk_mul_f32 %0, %1, %2 op_sel:[0,0] op_sel_hi:[0,1]\n\t"
      "v_pk_fma_f32 %0, %1, %2, %0 op_sel:[1,1,0] op_sel_hi:[1,0,1] neg_lo:[1,0,0]"
      : "=&v"(d) : "v"(u), "v"(v));
  return d;
}

__device__ __forceinline__ float2 loF(const float4& q) { return make_float2(q.x, q.y); }
__device__ __forceinline__ float2 hiF(const float4& q) { return make_float2(q.z, q.w); }

// chunk permutation: wave w handles chunks g_perm[w][0..2]; chunk c: N=c/2,
// spec offset (c&1)*64. Balanced so per-wave sum(d^2) is ~84 (range 76..100).
__device__ const signed char g_perm[16][3] = {
  {18,-1,-1},{19,-1,-1},{16, 0,-1},{17, 1,-1},{20,36,-1},{21,37,-1},
  {14, 6,34},{15, 7,35},{22,30,-1},{23,31,-1},{12, 8, 4},{13, 9, 5},
  {24,28,32},{25,29,33},{10,26, 2},{11,27, 3}
};

// ------------------- K0: sniff input dtype -------------------
__global__ void sniff_dtype(const void* p, int n_elems, int* flag) {
  __shared__ float red[256];
  const unsigned short* h = (const unsigned short*)p;
  int t = threadIdx.x;
  float mx = 0.f;
  for (int i = t; i < n_elems; i += 256) {
    unsigned short u = h[i];
    bf16 bv = *(const bf16*)&u;
    float v = fabsf(__bfloat162float(bv));
    if (!(v < 1e30f)) v = 1e30f;
    mx = fmaxf(mx, v);
  }
  red[t] = mx;
  __syncthreads();
  for (int off = 128; off > 0; off >>= 1) {
    if (t < off) red[t] = fmaxf(red[t], red[t + off]);
    __syncthreads();
  }
  if (t == 0) *flag = (red[0] > 1000.f) ? 1 : 0;  // 1 => buffer is really f32
}

// ------------------- K1: build all generators (REAL except S0) -------------------
__global__ void build_gens(float* rslots, float2* s0, const void* inp,
                           const void* w, const int* flag) {
  int s = blockIdx.x;
  int t = threadIdx.x;
  if (t >= 100) return;
  int isf32 = *flag;
  int i = t / 10, j = t % 10;
  if (s == NRSLOTS) {   // complex S0 generator
    float2 val = make_float2(0.f, 0.f);
    if (j == i + 2)      { float c = sqrtf((float)((i+1)*(i+2))); val.y = -0.25f*c; }
    else if (i == j + 2) { float c = sqrtf((float)((j+1)*(j+2))); val.y = -0.25f*c; }
    s0[t] = val;
    return;
  }
  float val = 0.f;
  if (s < R_SQ) {                       // input displacement, real: r(adag - a)
    float r = readv(inp, s, isf32);
    if (i == j + 1)      val =  r * sqrtf((float)(j+1));
    else if (j == i + 1) val = -r * sqrtf((float)(i+1));
  } else if (s < R_DS) {                // squeezer, real: 0.5 r (a^2 - adag^2)
    int k = s - R_SQ; int l = k >> 2; int m = k & 3;
    float r = readv(w, l*WSTRIDE + 16 + m, isf32);
    if (j == i + 2)      val =  0.5f*r*sqrtf((float)((i+1)*(i+2)));
    else if (i == j + 2) val = -0.5f*r*sqrtf((float)((j+1)*(j+2)));
  } else if (s < R_BS) {                // displacement radial part, real: rd(adag - a)
    int k = s - R_DS; int l = k >> 2; int m = k & 3;
    float rd = readv(w, l*WSTRIDE + 36 + m, isf32);
    if (i == j + 1)      val =  rd * sqrtf((float)(j+1));
    else if (j == i + 1) val = -rd * sqrtf((float)(i+1));
  } else {                              // BS block, real part (phase conjugated out)
    int rel = s - R_BS;
    int g = rel / 19; int N = rel % 19;
    int l = g / 12; int hf = (g % 12) / 6; int p = g % 6;
    float th = readv(w, l*WSTRIDE + (hf ? 20 : 0) + p, isf32);
    int lo = max(0, N - 9), hi = min(9, N);
    int d = hi - lo + 1;
    if (i < d && j < d) {
      if (i == j + 1)      val =  th * sqrtf((float)((lo + j + 1) * (N - lo - j)));
      else if (j == i + 1) val = -th * sqrtf((float)((lo + i + 1) * (N - lo - i)));
    }
  }
  rslots[(size_t)s * 100 + t] = val;
}

// ------------------- K2a: real expm (scaling-squaring + Taylor) -------------------
__global__ void expm_real(float* rslots) {
  __shared__ float T[100], Pm[100], R[100];
  __shared__ float rowsum[10];
  __shared__ int sshift;
  int s = blockIdx.x, t = threadIdx.x;
  int i = t / 10, j = t % 10;
  float* G = rslots + (size_t)s * 100;
  if (t < 100) T[t] = G[t];
  __syncthreads();
  if (t < 10) {
    float sum = 0.f;
    for (int c = 0; c < 10; ++c) sum += fabsf(T[t*10+c]);
    rowsum[t] = sum;
  }
  __syncthreads();
  if (t == 0) {
    float nm = 0.f;
    for (int r = 0; r < 10; ++r) nm = fmaxf(nm, rowsum[r]);
    int sc = 0;
    if (!(nm < 1e6f)) sc = 0;
    else if (nm > 0.25f) sc = (int)ceilf(log2f(nm * 4.f));
    sshift = min(max(sc, 0), 40);
  }
  __syncthreads();
  int sh = sshift;
  float scl = ldexpf(1.f, -sh);
  if (t < 100) {
    float z = T[t] * scl;
    T[t] = z; Pm[t] = z;
    R[t] = z + (i == j ? 1.f : 0.f);
  }
  __syncthreads();
  for (int k = 2; k <= 12; ++k) {
    float acc = 0.f;
    if (t < 100) {
      for (int c = 0; c < 10; ++c) acc += Pm[i*10+c] * T[c*10+j];
      acc *= 1.f / (float)k;
    }
    __syncthreads();
    if (t < 100) { Pm[t] = acc; R[t] += acc; }
    __syncthreads();
  }
  for (int q = 0; q < sh; ++q) {
    float acc = 0.f;
    if (t < 100) {
      for (int c = 0; c < 10; ++c) acc += R[i*10+c] * R[c*10+j];
    }
    __syncthreads();
    if (t < 100) R[t] = acc;
    __syncthreads();
  }
  if (t < 100) G[t] = R[t];
}

// ------------------- K2b: complex expm for S0 only -------------------
__global__ void expm_cplx(float2* G) {
  __shared__ float2 T[100], P[100], R[100];
  __shared__ float rowsum[10];
  __shared__ int sshift;
  int t = threadIdx.x;
  int i = t / 10, j = t % 10;
  if (t < 100) T[t] = G[t];
  __syncthreads();
  if (t < 10) {
    float sum = 0.f;
    for (int c = 0; c < 10; ++c) { float2 z = T[t*10+c]; sum += fabsf(z.x) + fabsf(z.y); }
    rowsum[t] = sum;
  }
  __syncthreads();
  if (t == 0) {
    float nm = 0.f;
    for (int r = 0; r < 10; ++r) nm = fmaxf(nm, rowsum[r]);
    int sc = 0;
    if (!(nm < 1e6f)) sc = 0;
    else if (nm > 0.25f) sc = (int)ceilf(log2f(nm * 4.f));
    sshift = min(max(sc, 0), 40);
  }
  __syncthreads();
  int sh = sshift;
  float scl = ldexpf(1.f, -sh);
  if (t < 100) {
    float2 z = T[t]; z.x *= scl; z.y *= scl;
    T[t] = z; P[t] = z;
    R[t] = make_float2(z.x + (i == j ? 1.f : 0.f), z.y);
  }
  __syncthreads();
  for (int k = 2; k <= 12; ++k) {
    float2 acc = make_float2(0.f, 0.f);
    if (t < 100) {
      for (int c = 0; c < 10; ++c) {
        float2 a = P[i*10+c], b = T[c*10+j];
        acc.x += a.x*b.x - a.y*b.y;
        acc.y += a.x*b.y + a.y*b.x;
      }
      float inv = 1.f / (float)k;
      acc.x *= inv; acc.y *= inv;
    }
    __syncthreads();
    if (t < 100) { P[t] = acc; R[t].x += acc.x; R[t].y += acc.y; }
    __syncthreads();
  }
  for (int q = 0; q < sh; ++q) {
    float2 acc = make_float2(0.f, 0.f);
    if (t < 100) {
      for (int c = 0; c < 10; ++c) {
        float2 a = R[i*10+c], b = R[c*10+j];
        acc.x += a.x*b.x - a.y*b.y;
        acc.y += a.x*b.y + a.y*b.x;
      }
    }
    __syncthreads();
    if (t < 100) R[t] = acc;
    __syncthreads();
  }
  if (t < 100) G[t] = R[t];
}

// per-gate fused output-rotation coefficients (diagonal phases merged across gates):
//   angle(row) = f0*hi10 + f1*lo10 + f3*N + fdc*(lo+row)
__device__ __forceinline__ void gate_fs(const void* w, int isf32, int l, int half,
                                        int g, float& f0, float& f1, float& f3,
                                        float& fdc) {
  int po = l*WSTRIDE + (half ? 26 : 6);   // phases ph1/ph2
  int vo = l*WSTRIDE + (half ? 32 : 12);  // vphases vp1/vp2
  f0 = 0.f; f1 = 0.f; f3 = 0.f;
  switch (g) {
    case 0: fdc = readv(w, po+0, isf32) - readv(w, po+1, isf32); break;
    case 1: fdc = readv(w, po+1, isf32) - readv(w, po+2, isf32); break;
    case 2: f0 = -readv(w, po+3, isf32); fdc = readv(w, po+2, isf32); break;
    case 3: fdc = readv(w, po+3, isf32) - readv(w, po+4, isf32); break;
    case 4: f1 = -readv(w, po+5, isf32); fdc = readv(w, po+4, isf32); break;
    default: {
      float vp0 = readv(w, vo+0, isf32), vp1 = readv(w, vo+1, isf32);
      float vp2 = readv(w, vo+2, isf32), vp3 = readv(w, vo+3, isf32);
      if (half) {   // absorb displacement pre-phases e^{-i phd n}
        vp0 -= readv(w, l*WSTRIDE+40+0, isf32);
        vp1 -= readv(w, l*WSTRIDE+40+1, isf32);
        vp2 -= readv(w, l*WSTRIDE+40+2, isf32);
        vp3 -= readv(w, l*WSTRIDE+40+3, isf32);
      }
      f0 = vp0; f1 = vp1; f3 = vp3;
      fdc = vp2 + readv(w, po+5, isf32) - vp3;
    }
  }
}

// ------------------- K2c: build ALL 8 halves' rotation LUTs (once, tiny) -------------------
__global__ void build_luts(float2* lutg, const void* w, const int* flag) {
  const int h = blockIdx.x;            // 0..7 = l*2 + half
  const int t = threadIdx.x;           // 0..319
  const int l = h >> 1, half = h & 1;
  const int isf32 = *flag;
  const int po = l*WSTRIDE + (half ? 26 : 6);
  float2* lb = lutg + (size_t)h * LUT_PAD;
  if (t < LUT_N) {
    float ang = 0.f;
    if (t < 120) {
      int isB = (t >= 60);
      int id = isB ? t - 60 : t;
      int g = id / 10, q = id % 10;
      float f0, f1, f3, fd;
      gate_fs(w, isf32, l, half, g, f0, f1, f3, fd);
      ang = (isB ? f1 : f0) * (float)q;
    } else if (t < 234) {
      int id = t - 120; int g = id / 19, N = id % 19;
      float f0, f1, f3, fd;
      gate_fs(w, isf32, l, half, g, f0, f1, f3, fd);
      int lo = max(0, N - 9);
      ang = f3 * (float)N + fd * (float)lo;
    } else if (t < 253) {
      int N = t - 234; int lo = max(0, N - 9);
      ang = -readv(w, po + 0, isf32) * (float)lo;
    } else if (t < 259) {
      int g = t - 253;
      float f0, f1, f3, fd;
      gate_fs(w, isf32, l, half, g, f0, f1, f3, fd);
      ang = fd;
    } else if (t == 259) {
      ang = -readv(w, po + 0, isf32);
    } else {
      int id = t - 260; int m = id / 10, q = id % 10;
      if (half) {
        float kap = readv(w, l*WSTRIDE + 44 + m, isf32);
        float pd  = readv(w, l*WSTRIDE + 40 + m, isf32);
        ang = kap * (float)(q*q) + pd * (float)q;
      }
    }
    float sn, cs; sincosf(ang, &sn, &cs);
    lb[t] = make_float2(cs, sn);
  } else if (t < LUT_PAD) {
    lb[t] = make_float2(1.f, 0.f);     // pad entries: identity (never used)
  }
}

#define LOADQ(DST, P) do { _Pragma("unroll") \
  for (int q_ = 0; q_ < 5; ++q_) DST[q_] = Uq[(P)*5 + q_]; } while (0)

// ---- BS gate: 2-deep cross-chunk pipeline (chunk r+1's state reads issue
// before chunk r's compute). Chunks partition the state by (N,spec) for this
// gate's axes — no other wave writes this wave's chunk elements during the
// region (proven correct in an earlier round), so the early reads are safe.
#define BS_DECL(IDX, C)                                                        \
  int N##IDX = 0, sd##IDX = 0, h##IDX = 0, p##IDX = 0;                         \
  bool ok##IDX = false; float2* b##IDX = st;                                   \
  if ((C) >= 0) {                                                              \
    N##IDX = (C) >> 1;                                                         \
    int spec_ = (((C) & 1) << 6) + lane;                                       \
    int lo_ = max(0, N##IDX - 9);                                              \
    sd##IDX = __builtin_amdgcn_readfirstlane(min(9, N##IDX) - lo_ + 1);        \
    ok##IDX = (spec_ < 100);                                                   \
    int sp_ = ok##IDX ? spec_ : 0;                                             \
    h##IDX = sp_ / 10; p##IDX = sp_ % 10;                                      \
    b##IDX = st + h##IDX*sA + p##IDX*sB + lo_*sI + (N##IDX - lo_)*sJ;          \
  }

#define BS_LOADV(VV, IDX)                                                      \
  { _Pragma("unroll")                                                          \
    for (int k = 0; k < 10; ++k)                                               \
      VV[k] = (k < sd##IDX && ok##IDX) ? b##IDX[k*se] : make_float2(0.f,0.f); }

#define BS_PAIR2(UA, R0, VV)                                                   \
  {                                                                            \
    float2 a0 = make_float2(0.f,0.f), a1 = make_float2(0.f,0.f);               \
    _Pragma("unroll")                                                          \
    for (int j = 0; j < 5; ++j) if (2*j < sd) {                                \
      const float2 m0 = (j==0)?loF(UA[0]):(j==1)?hiF(UA[0]):(j==2)?loF(UA[1])  \
                        :(j==3)?hiF(UA[1]):loF(UA[2]);                         \
      const float2 m1 = (j==0)?hiF(UA[2]):(j==1)?loF(UA[3]):(j==2)?hiF(UA[3])  \
                        :(j==3)?loF(UA[4]):hiF(UA[4]);                         \
      rmacL(a0, m0, VV[2*j]); rmacH(a0, m0, VV[2*j+1]);                        \
      rmacL(a1, m1, VV[2*j]); rmacH(a1, m1, VV[2*j+1]);                        \
    }                                                                          \
    a0 = cmul(a0, rot); rot = cmul(rot, step);                                 \
    if (okx) base[(R0)*se] = a0;                                               \
    if ((R0) + 1 < sd) {                                                       \
      a1 = cmul(a1, rot); rot = cmul(rot, step);                               \
      if (okx) base[((R0)+1)*se] = a1;                                         \
    }                                                                          \
  }

#define BS_COMPC(VV, IDX)                                                      \
  if (sd##IDX > 0) {                                                           \
    const int sd = sd##IDX; const bool okx = ok##IDX;                          \
    float2* base = b##IDX;                                                     \
    if (INROT) {                                                               \
      float2 ir = L[LUT_I + N##IDX];                                           \
      _Pragma("unroll")                                                        \
      for (int k = 0; k < 10; ++k)                                             \
        if (k < sd) { VV[k] = cmul(VV[k], ir); ir = cmul(ir, istep); }         \
    }                                                                          \
    float2 rot = cmul(cmul(L[LUT_A + g*10 + h##IDX],                           \
                           L[LUT_B + g*10 + p##IDX]),                          \
                      L[LUT_C + g*19 + N##IDX]);                               \
    const float4* Uq = (const float4*)(Ub + N##IDX*100);                       \
    float4 ua[5], ub2[5];                                                      \
    LOADQ(ua, 0);                                                              \
    _Pragma("unroll")                                                          \
    for (int p = 0; p < 5; p += 2) {                                           \
      if (2*p < sd) {                                                          \
        if (2*p + 2 < sd) LOADQ(ub2, p + 1);                                   \
        BS_PAIR2(ua, 2*p, VV)                                                  \
      }                                                                        \
      if (2*p + 2 < sd) {                                                      \
        if (2*p + 4 < sd) LOADQ(ua, p + 2);                                    \
        BS_PAIR2(ub2, 2*p + 2, VV)                                             \
      }                                                                        \
    }                                                                          \
  }

template<int sI, int sJ, int sA, int sB, bool INROT>
__device__ __forceinline__ void bs_gate(
    float2* st, const float* __restrict__ Ub, const float2* __restrict__ L,
    int g, int lane, int ch0, int ch1, int ch2)
{
  constexpr int se = sI - sJ;
  const float2 step  = L[LUT_S + g];
  const float2 istep = INROT ? L[LUT_IS] : make_float2(1.f, 0.f);
  float2 vA[10], vB[10];
  BS_DECL(0, ch0)
  BS_DECL(1, ch1)
  BS_DECL(2, ch2)
  BS_LOADV(vA, 0)       // chunk 0 state reads
  BS_LOADV(vB, 1)       // chunk 1 reads fly under chunk 0 compute
  BS_COMPC(vA, 0)
  BS_LOADV(vA, 2)       // chunk 2 reads fly under chunk 1 compute (reuse vA)
  BS_COMPC(vB, 1)
  BS_COMPC(vA, 2)
}

#define SM_PAIR(UA, R0)                                                        \
  {                                                                            \
    float2 a0 = make_float2(0.f,0.f), a1 = make_float2(0.f,0.f);               \
    _Pragma("unroll")                                                          \
    for (int j = 0; j < 5; ++j) {                                              \
      const float2 m0 = (j==0)?loF(UA[0]):(j==1)?hiF(UA[0]):(j==2)?loF(UA[1])  \
                        :(j==3)?hiF(UA[1]):loF(UA[2]);                         \
      const float2 m1 = (j==0)?hiF(UA[2]):(j==1)?loF(UA[3]):(j==2)?hiF(UA[3])  \
                        :(j==3)?loF(UA[4]):hiF(UA[4]);                         \
      rmacL(a0, m0, v[2*j]); rmacH(a0, m0, v[2*j+1]);                          \
      rmacL(a1, m1, v[2*j]); rmacH(a1, m1, v[2*j+1]);                          \
    }                                                                          \
    if (KERR) {                                                                \
      a0 = cmul(a0, cmul(kb, L[LUT_K + 30 + (R0)]));                           \
      a1 = cmul(a1, cmul(kb, L[LUT_K + 30 + (R0) + 1]));                       \
    }                                                                          \
    base[(R0)*sM]   = a0;                                                      \
    base[((R0)+1)*sM] = a1;                                                    \
  }

// ---- single-mode gate: REAL 10x10 matvec, optional fused Kerr+phd rotation ----
template<int sM, int pA, int pB, int pC, bool KERR>
__device__ __forceinline__ void sm_gate(
    float2* st, const float* __restrict__ U, const float2* __restrict__ L,
    bool smv, int q0, int q1, int q2)
{
  if (!smv) return;
  float2* base = st + q0*pA + q1*pB + q2*pC;
  float2 kb = make_float2(1.f, 0.f);
  if (KERR) kb = cmul(cmul(L[LUT_K + q0], L[LUT_K + 10 + q1]),
                      L[LUT_K + 20 + q2]);
  float2 v[10];
#pragma unroll
  for (int k = 0; k < 10; ++k) v[k] = base[k*sM];
  const float4* Uq = (const float4*)U;
  float4 ua[5], ub[5];
  LOADQ(ua, 0);
#pragma unroll
  for (int p = 0; p < 5; p += 2) {
    {
      if (p < 4) LOADQ(ub, p + 1);
      SM_PAIR(ua, 2*p);
    }
    if (p + 1 < 5) {
      if (p + 2 < 5) LOADQ(ua, p + 2);
      SM_PAIR(ub, 2*(p + 1));
    }
  }
}

// ------------------- K3: fused circuit — one block per batch, state in LDS -------------------
// LDS: state 88.8K + smU 12.8K + bsU(dbuf) 15.2K + luts 20.5K + misc ~0.6K = ~137.9K.
// LDS forces 1 block/CU = 4 waves/EU, so waves_per_eu(4,4) costs no occupancy and
// raises the register budget to 512/4 = 128 VGPRs (the plain __launch_bounds__
// second arg left the allocator at a hard 64-reg target: all prior spills showed
// VGPR_Count=64 + scratch traffic).
__global__ __launch_bounds__(1024) __attribute__((amdgpu_waves_per_eu(4, 4)))
void fused_circuit(
    const float* __restrict__ rslots, const float2* __restrict__ s0,
    const float2* __restrict__ lutg, float* __restrict__ out)
{
  __shared__ float2 st[ST_PHYS];                 // ~89 KB swizzled state
  __shared__ __align__(16) float smU[3200];      // all 32 single-mode REAL U's
  __shared__ __align__(16) float bsU[2*1900];    // double-buffered REAL BS gate
  __shared__ __align__(16) float2 lut[8][LUT_PAD];  // all 8 halves' rotation LUTs
  __shared__ float2 psi[4][10];
  __shared__ float redw[64];
  const int b = blockIdx.x, t = threadIdx.x;
  const int wv = t >> 6, lane = t & 63;

  const int wvu = __builtin_amdgcn_readfirstlane(wv);
  const int ch0 = __builtin_amdgcn_readfirstlane((int)g_perm[wvu][0]);
  const int ch1 = __builtin_amdgcn_readfirstlane((int)g_perm[wvu][1]);
  const int ch2 = __builtin_amdgcn_readfirstlane((int)g_perm[wvu][2]);
  const bool smv = (t < 1000);
  const int q0 = t / 100, q1 = (t / 10) % 10, q2 = t % 10;

  // ---- initial product state (Dm real @ complex S0 column 0) + staging ----
  if (t < 40) {
    int m = t / 10, r = t % 10;
    const float* Dmr = rslots + (size_t)(R_DM + b*4 + m) * 100;
    float2 acc = make_float2(0.f, 0.f);
    for (int c = 0; c < 10; ++c) {
      float a = Dmr[r*10 + c];
      float2 vv = s0[c * 10];   // S0 column 0
      acc.x += a * vv.x;
      acc.y += a * vv.y;
    }
    psi[m][r] = acc;
  }
  for (int i = t; i < 800; i += 1024)           // smU: 3200 floats = 800 quads
    ((float4*)smU)[i] = ((const float4*)(rslots + (size_t)R_SQ * 100))[i];
  for (int i = t; i < 475; i += 1024)           // bsU gate 0: 1900 floats = 475 quads
    ((float4*)bsU)[i] = ((const float4*)(rslots + (size_t)R_BS * 100))[i];
  for (int i = t; i < 8 * LUT_PAD / 2; i += 1024)  // LUTs: 2560 float2 = 1280 quads
    ((float4*)lut)[i] = ((const float4*)lutg)[i];
  __syncthreads();
  for (int e = t; e < 10000; e += 1024) {
    int ph = e + e/10 + e/100;
    float2 z  = psi[0][e/1000];
    float2 w1 = psi[1][(e/100)%10];
    float2 r1 = make_float2(z.x*w1.x - z.y*w1.y, z.x*w1.y + z.y*w1.x);
    float2 w2 = psi[2][(e/10)%10];
    float2 r2 = make_float2(r1.x*w2.x - r1.y*w2.y, r1.x*w2.y + r1.y*w2.x);
    float2 w3 = psi[3][e%10];
    st[ph] = make_float2(r2.x*w3.x - r2.y*w3.y, r2.x*w3.y + r2.y*w3.x);
  }
  __syncthreads();

  // split prefetch: global->reg at gate start, reg->LDS after compute.
  float4 pf;
  auto pf_load = [&](int next) {
    if (next < 48 && t < 475)
      pf = ((const float4*)(rslots + (size_t)(R_BS + next*19) * 100))[t];
  };
  auto pf_store = [&](int next) {
    if (next < 48 && t < 475)
      ((float4*)(bsU + (next & 1) * 1900))[t] = pf;
  };

  // ---- circuit ----
#pragma unroll 1
  for (int l = 0; l < NLAYERS; ++l) {
#pragma unroll 1
    for (int half = 0; half < 2; ++half) {
      const int g6 = l*12 + half*6;
      const float2* L = lut[(l << 1) | half];

      pf_load(g6+1);
      bs_gate<F0,F1,F2,F3,true >(st, bsU+((g6+0)&1)*1900, L, 0, lane, ch0,ch1,ch2);
      pf_store(g6+1);
      __syncthreads();
      pf_load(g6+2);
      bs_gate<F0,F2,F1,F3,false>(st, bsU+((g6+1)&1)*1900, L, 1, lane, ch0,ch1,ch2);
      pf_store(g6+2);
      __syncthreads();
      pf_load(g6+3);
      bs_gate<F0,F3,F1,F2,false>(st, bsU+((g6+2)&1)*1900, L, 2, lane, ch0,ch1,ch2);
      pf_store(g6+3);
      __syncthreads();
      pf_load(g6+4);
      bs_gate<F1,F2,F0,F3,false>(st, bsU+((g6+3)&1)*1900, L, 3, lane, ch0,ch1,ch2);
      pf_store(g6+4);
      __syncthreads();
      pf_load(g6+5);
      bs_gate<F1,F3,F0,F2,false>(st, bsU+((g6+4)&1)*1900, L, 4, lane, ch0,ch1,ch2);
      pf_store(g6+5);
      __syncthreads();
      pf_load(g6+6);
      bs_gate<F2,F3,F0,F1,false>(st, bsU+((g6+5)&1)*1900, L, 5, lane, ch0,ch1,ch2);
      pf_store(g6+6);
      __syncthreads();

      const int ub_ = (half == 0) ? (l*4) : (16 + l*4);
      sm_gate<F0,F1,F2,F3,false>(st, smU+(ub_+0)*100, L, smv, q0,q1,q2);
      __syncthreads();
      sm_gate<F1,F0,F2,F3,false>(st, smU+(ub_+1)*100, L, smv, q0,q1,q2);
      __syncthreads();
      sm_gate<F2,F0,F1,F3,false>(st, smU+(ub_+2)*100, L, smv, q0,q1,q2);
      __syncthreads();
      if (half)
        sm_gate<F3,F0,F1,F2,true >(st, smU+(ub_+3)*100, L, smv, q0,q1,q2);
      else
        sm_gate<F3,F0,F1,F2,false>(st, smU+(ub_+3)*100, L, smv, q0,q1,q2);
      __syncthreads();
    }
  }

  // ---- photon-number expectations (wave shuffle reduce) ----
  float a0 = 0.f, a1 = 0.f, a2 = 0.f, a3 = 0.f;
  for (int e = t; e < 10000; e += 1024) {
    int ph = e + e/10 + e/100;
    float2 z = st[ph];
    float pz = z.x*z.x + z.y*z.y;
    a0 += pz * (float)(e/1000);
    a1 += pz * (float)((e/100)%10);
    a2 += pz * (float)((e/10)%10);
    a3 += pz * (float)(e%10);
  }
  for (int off2 = 32; off2 > 0; off2 >>= 1) {
    a0 += __shfl_down(a0, off2, 64);
    a1 += __shfl_down(a1, off2, 64);
    a2 += __shfl_down(a2, off2, 64);
    a3 += __shfl_down(a3, off2, 64);
  }
  if (lane == 0) {
    redw[wv*4+0] = a0; redw[wv*4+1] = a1;
    redw[wv*4+2] = a2; redw[wv*4+3] = a3;
  }
  __syncthreads();
  if (t < 4) {
    float s = 0.f;
    for (int ww = 0; ww < 16; ++ww) s += redw[ww*4 + t];
    out[b*4 + t] = s;
  }
}

extern "C" void kernel_launch(void* const* d_in, const int* in_sizes, int n_in,
                              void* d_out, int out_size, void* d_ws, size_t ws_size,
                              hipStream_t stream) {
  const void* inp = d_in[0];
  const void* w   = d_in[1];
  float* out = (float*)d_out;                 // reference output dtype is float32
  int*    flag   = (int*)d_ws;                // 16-byte header
  float2* s0     = (float2*)((char*)d_ws + 16);          // complex S0 (100 float2)
  float*  rslots = (float*)((char*)d_ws + 1024);         // 1968 real 10x10 slots
  float2* lutg   = (float2*)((char*)d_ws + 1024 + NRSLOTS*400);  // 8 x 320 float2

  sniff_dtype<<<dim3(1), dim3(256), 0, stream>>>(inp, in_sizes[0], flag);
  build_gens<<<dim3(NRSLOTS + 1), dim3(128), 0, stream>>>(rslots, s0, inp, w, flag);
  build_luts<<<dim3(8), dim3(LUT_PAD), 0, stream>>>(lutg, w, flag);
  expm_real<<<dim3(NRSLOTS), dim3(128), 0, stream>>>(rslots);
  expm_cplx<<<dim3(1), dim3(128), 0, stream>>>(s0);
  fused_circuit<<<dim3(NB), dim3(1024), 0, stream>>>(rslots, s0, lutg, out);
}

// Round 7
// 337.611 us; speedup vs baseline: 1.5375x; 1.5375x over previous
//
#include <hip/hip_runtime.h>
#include <hip/hip_bf16.h>

#define CUT 10
#define NB 256
#define NLAYERS 4
#define WSTRIDE 48

// real slot map (each real slot = 10x10 float, 100 floats)
#define R_DM 0        // 1024 input-displacement matrices (real)
#define R_SQ 1024     // 16 squeezers (l*4+m) (real)
#define R_DS 1040     // 16 displacement radial parts (l*4+m) (real)
#define R_BS 1056     // 48 gates * 19 photon-number blocks (real)
#define NRSLOTS 1968  // real slots; +1 extra build block for complex S0

// physical per-mode strides, chosen for LDS bank uniformity:
// all coefficients ODD mod 16 -> (11, 3, 13, 1); every gate's fast-varying
// lane digit has multiplier 1/3/13 (uniform residue coverage), unlike the old
// (1110,111,11,1) = (6,15,11,1) whose "11" fast digit clustered banks.
// Injectivity: F2 > 9, F1 > 9*(F2+1)=126, F0 > 9*(F1+F2+1)=1305.  Max ph = 13068.
#define F0 1307
#define F1 131
#define F2 13
#define F3 1
#define ST_PHYS 13069

// rotation LUT layout (float2 entries = e^{i*ang})
#define LUT_A  0     // [6][10] e^{i f0_g * h}
#define LUT_B  60    // [6][10] e^{i f1_g * l}
#define LUT_C  120   // [6][19] e^{i (f3_g N + fdc_g lo(N))}
#define LUT_I  234   // [19]    e^{-i phi1 lo(N)}   (gate-0 input rot start)
#define LUT_S  253   // [6]     e^{i fdc_g}         (row step)
#define LUT_IS 259   // [1]     e^{-i phi1}         (input rot step)
#define LUT_K  260   // [4][10] e^{i (kap_m q^2 + phd_m q)}
#define LUT_N  300
#define LUT_PAD 320

typedef __hip_bfloat16 bf16;

// read element i of a buffer whose dtype (f32 vs bf16) was sniffed at runtime
__device__ __forceinline__ float readv(const void* p, int i, int isf32) {
  if (isf32) return ((const float*)p)[i];
  return __bfloat162float(((const bf16*)p)[i]);
}

// real MAC: acc += m * v (complex v, real m), m = mm.x (rmacL) or mm.y (rmacH)
// -> ONE v_pk_fma_f32 per complex MAC (the real-algebra payoff)
__device__ __forceinline__ void rmacL(float2& a, float2 mm, float2 v) {
  asm("v_pk_fma_f32 %0, %1, %2, %0 op_sel:[0,0,0] op_sel_hi:[0,1,1]"
      : "+v"(a) : "v"(mm), "v"(v));
}
__device__ __forceinline__ void rmacH(float2& a, float2 mm, float2 v) {
  asm("v_pk_fma_f32 %0, %1, %2, %0 op_sel:[1,0,0] op_sel_hi:[1,1,1]"
      : "+v"(a) : "v"(mm), "v"(v));
}

// full complex multiply d = u*v : 2 packed ops
__device__ __forceinline__ float2 cmul(float2 u, float2 v) {
  float2 d;
  asm("v_pk_mul_f32 %0, %1, %2 op_sel:[0,0] op_sel_hi:[0,1]\n\t"
      "v_pk_fma_f32 %0, %1, %2, %0 op_sel:[1,1,0] op_sel_hi:[1,0,1] neg_lo:[1,0,0]"
      : "=&v"(d) : "v"(u), "v"(v));
  return d;
}

__device__ __forceinline__ float2 loF(const float4& q) { return make_float2(q.x, q.y); }
__device__ __forceinline__ float2 hiF(const float4& q) { return make_float2(q.z, q.w); }

// physical address from linear Fock index e = ((n0*10+n1)*10+n2)*10+n3
__device__ __forceinline__ int phys_of(int e) {
  int n0 = e / 1000, r = e % 1000;
  int n1 = r / 100;  r %= 100;
  int n2 = r / 10;
  int n3 = r % 10;
  return n0*F0 + n1*F1 + n2*F2 + n3*F3;
}

// chunk permutation: wave w handles chunks g_perm[w][0..2]; chunk c: N=c/2,
// spec offset (c&1)*64. Balanced so per-wave sum(d^2) is ~84 (range 76..100).
__device__ const signed char g_perm[16][3] = {
  {18,-1,-1},{19,-1,-1},{16, 0,-1},{17, 1,-1},{20,36,-1},{21,37,-1},
  {14, 6,34},{15, 7,35},{22,30,-1},{23,31,-1},{12, 8, 4},{13, 9, 5},
  {24,28,32},{25,29,33},{10,26, 2},{11,27, 3}
};

// ------------------- K0: sniff input dtype -------------------
__global__ void sniff_dtype(const void* p, int n_elems, int* flag) {
  __shared__ float red[256];
  const unsigned short* h = (const unsigned short*)p;
  int t = threadIdx.x;
  float mx = 0.f;
  for (int i = t; i < n_elems; i += 256) {
    unsigned short u = h[i];
    bf16 bv = *(const bf16*)&u;
    float v = fabsf(__bfloat162float(bv));
    if (!(v < 1e30f)) v = 1e30f;
    mx = fmaxf(mx, v);
  }
  red[t] = mx;
  __syncthreads();
  for (int off = 128; off > 0; off >>= 1) {
    if (t < off) red[t] = fmaxf(red[t], red[t + off]);
    __syncthreads();
  }
  if (t == 0) *flag = (red[0] > 1000.f) ? 1 : 0;  // 1 => buffer is really f32
}

// ------------------- K1: build all generators (REAL except S0) -------------------
__global__ void build_gens(float* rslots, float2* s0, const void* inp,
                           const void* w, const int* flag) {
  int s = blockIdx.x;
  int t = threadIdx.x;
  if (t >= 100) return;
  int isf32 = *flag;
  int i = t / 10, j = t % 10;
  if (s == NRSLOTS) {   // complex S0 generator
    float2 val = make_float2(0.f, 0.f);
    if (j == i + 2)      { float c = sqrtf((float)((i+1)*(i+2))); val.y = -0.25f*c; }
    else if (i == j + 2) { float c = sqrtf((float)((j+1)*(j+2))); val.y = -0.25f*c; }
    s0[t] = val;
    return;
  }
  float val = 0.f;
  if (s < R_SQ) {                       // input displacement, real: r(adag - a)
    float r = readv(inp, s, isf32);
    if (i == j + 1)      val =  r * sqrtf((float)(j+1));
    else if (j == i + 1) val = -r * sqrtf((float)(i+1));
  } else if (s < R_DS) {                // squeezer, real: 0.5 r (a^2 - adag^2)
    int k = s - R_SQ; int l = k >> 2; int m = k & 3;
    float r = readv(w, l*WSTRIDE + 16 + m, isf32);
    if (j == i + 2)      val =  0.5f*r*sqrtf((float)((i+1)*(i+2)));
    else if (i == j + 2) val = -0.5f*r*sqrtf((float)((j+1)*(j+2)));
  } else if (s < R_BS) {                // displacement radial part, real: rd(adag - a)
    int k = s - R_DS; int l = k >> 2; int m = k & 3;
    float rd = readv(w, l*WSTRIDE + 36 + m, isf32);
    if (i == j + 1)      val =  rd * sqrtf((float)(j+1));
    else if (j == i + 1) val = -rd * sqrtf((float)(i+1));
  } else {                              // BS block, real part (phase conjugated out)
    int rel = s - R_BS;
    int g = rel / 19; int N = rel % 19;
    int l = g / 12; int hf = (g % 12) / 6; int p = g % 6;
    float th = readv(w, l*WSTRIDE + (hf ? 20 : 0) + p, isf32);
    int lo = max(0, N - 9), hi = min(9, N);
    int d = hi - lo + 1;
    if (i < d && j < d) {
      if (i == j + 1)      val =  th * sqrtf((float)((lo + j + 1) * (N - lo - j)));
      else if (j == i + 1) val = -th * sqrtf((float)((lo + i + 1) * (N - lo - i)));
    }
  }
  rslots[(size_t)s * 100 + t] = val;
}

// ------------------- K2a: real expm (scaling-squaring + Taylor) -------------------
__global__ void expm_real(float* rslots) {
  __shared__ float T[100], Pm[100], R[100];
  __shared__ float rowsum[10];
  __shared__ int sshift;
  int s = blockIdx.x, t = threadIdx.x;
  int i = t / 10, j = t % 10;
  float* G = rslots + (size_t)s * 100;
  if (t < 100) T[t] = G[t];
  __syncthreads();
  if (t < 10) {
    float sum = 0.f;
    for (int c = 0; c < 10; ++c) sum += fabsf(T[t*10+c]);
    rowsum[t] = sum;
  }
  __syncthreads();
  if (t == 0) {
    float nm = 0.f;
    for (int r = 0; r < 10; ++r) nm = fmaxf(nm, rowsum[r]);
    int sc = 0;
    if (!(nm < 1e6f)) sc = 0;
    else if (nm > 0.25f) sc = (int)ceilf(log2f(nm * 4.f));
    sshift = min(max(sc, 0), 40);
  }
  __syncthreads();
  int sh = sshift;
  float scl = ldexpf(1.f, -sh);
  if (t < 100) {
    float z = T[t] * scl;
    T[t] = z; Pm[t] = z;
    R[t] = z + (i == j ? 1.f : 0.f);
  }
  __syncthreads();
  for (int k = 2; k <= 12; ++k) {
    float acc = 0.f;
    if (t < 100) {
      for (int c = 0; c < 10; ++c) acc += Pm[i*10+c] * T[c*10+j];
      acc *= 1.f / (float)k;
    }
    __syncthreads();
    if (t < 100) { Pm[t] = acc; R[t] += acc; }
    __syncthreads();
  }
  for (int q = 0; q < sh; ++q) {
    float acc = 0.f;
    if (t < 100) {
      for (int c = 0; c < 10; ++c) acc += R[i*10+c] * R[c*10+j];
    }
    __syncthreads();
    if (t < 100) R[t] = acc;
    __syncthreads();
  }
  if (t < 100) G[t] = R[t];
}

// ------------------- K2b: complex expm for S0 only -------------------
__global__ void expm_cplx(float2* G) {
  __shared__ float2 T[100], P[100], R[100];
  __shared__ float rowsum[10];
  __shared__ int sshift;
  int t = threadIdx.x;
  int i = t / 10, j = t % 10;
  if (t < 100) T[t] = G[t];
  __syncthreads();
  if (t < 10) {
    float sum = 0.f;
    for (int c = 0; c < 10; ++c) { float2 z = T[t*10+c]; sum += fabsf(z.x) + fabsf(z.y); }
    rowsum[t] = sum;
  }
  __syncthreads();
  if (t == 0) {
    float nm = 0.f;
    for (int r = 0; r < 10; ++r) nm = fmaxf(nm, rowsum[r]);
    int sc = 0;
    if (!(nm < 1e6f)) sc = 0;
    else if (nm > 0.25f) sc = (int)ceilf(log2f(nm * 4.f));
    sshift = min(max(sc, 0), 40);
  }
  __syncthreads();
  int sh = sshift;
  float scl = ldexpf(1.f, -sh);
  if (t < 100) {
    float2 z = T[t]; z.x *= scl; z.y *= scl;
    T[t] = z; P[t] = z;
    R[t] = make_float2(z.x + (i == j ? 1.f : 0.f), z.y);
  }
  __syncthreads();
  for (int k = 2; k <= 12; ++k) {
    float2 acc = make_float2(0.f, 0.f);
    if (t < 100) {
      for (int c = 0; c < 10; ++c) {
        float2 a = P[i*10+c], b = T[c*10+j];
        acc.x += a.x*b.x - a.y*b.y;
        acc.y += a.x*b.y + a.y*b.x;
      }
      float inv = 1.f / (float)k;
      acc.x *= inv; acc.y *= inv;
    }
    __syncthreads();
    if (t < 100) { P[t] = acc; R[t].x += acc.x; R[t].y += acc.y; }
    __syncthreads();
  }
  for (int q = 0; q < sh; ++q) {
    float2 acc = make_float2(0.f, 0.f);
    if (t < 100) {
      for (int c = 0; c < 10; ++c) {
        float2 a = R[i*10+c], b = R[c*10+j];
        acc.x += a.x*b.x - a.y*b.y;
        acc.y += a.x*b.y + a.y*b.x;
      }
    }
    __syncthreads();
    if (t < 100) R[t] = acc;
    __syncthreads();
  }
  if (t < 100) G[t] = R[t];
}

// per-gate fused output-rotation coefficients (diagonal phases merged across gates):
//   angle(row) = f0*hi10 + f1*lo10 + f3*N + fdc*(lo+row)
__device__ __forceinline__ void gate_fs(const void* w, int isf32, int l, int half,
                                        int g, float& f0, float& f1, float& f3,
                                        float& fdc) {
  int po = l*WSTRIDE + (half ? 26 : 6);   // phases ph1/ph2
  int vo = l*WSTRIDE + (half ? 32 : 12);  // vphases vp1/vp2
  f0 = 0.f; f1 = 0.f; f3 = 0.f;
  switch (g) {
    case 0: fdc = readv(w, po+0, isf32) - readv(w, po+1, isf32); break;
    case 1: fdc = readv(w, po+1, isf32) - readv(w, po+2, isf32); break;
    case 2: f0 = -readv(w, po+3, isf32); fdc = readv(w, po+2, isf32); break;
    case 3: fdc = readv(w, po+3, isf32) - readv(w, po+4, isf32); break;
    case 4: f1 = -readv(w, po+5, isf32); fdc = readv(w, po+4, isf32); break;
    default: {
      float vp0 = readv(w, vo+0, isf32), vp1 = readv(w, vo+1, isf32);
      float vp2 = readv(w, vo+2, isf32), vp3 = readv(w, vo+3, isf32);
      if (half) {   // absorb displacement pre-phases e^{-i phd n}
        vp0 -= readv(w, l*WSTRIDE+40+0, isf32);
        vp1 -= readv(w, l*WSTRIDE+40+1, isf32);
        vp2 -= readv(w, l*WSTRIDE+40+2, isf32);
        vp3 -= readv(w, l*WSTRIDE+40+3, isf32);
      }
      f0 = vp0; f1 = vp1; f3 = vp3;
      fdc = vp2 + readv(w, po+5, isf32) - vp3;
    }
  }
}

// ------------------- K2c: build ALL 8 halves' rotation LUTs (once, tiny) -------------------
__global__ void build_luts(float2* lutg, const void* w, const int* flag) {
  const int h = blockIdx.x;            // 0..7 = l*2 + half
  const int t = threadIdx.x;           // 0..319
  const int l = h >> 1, half = h & 1;
  const int isf32 = *flag;
  const int po = l*WSTRIDE + (half ? 26 : 6);
  float2* lb = lutg + (size_t)h * LUT_PAD;
  if (t < LUT_N) {
    float ang = 0.f;
    if (t < 120) {
      int isB = (t >= 60);
      int id = isB ? t - 60 : t;
      int g = id / 10, q = id % 10;
      float f0, f1, f3, fd;
      gate_fs(w, isf32, l, half, g, f0, f1, f3, fd);
      ang = (isB ? f1 : f0) * (float)q;
    } else if (t < 234) {
      int id = t - 120; int g = id / 19, N = id % 19;
      float f0, f1, f3, fd;
      gate_fs(w, isf32, l, half, g, f0, f1, f3, fd);
      int lo = max(0, N - 9);
      ang = f3 * (float)N + fd * (float)lo;
    } else if (t < 253) {
      int N = t - 234; int lo = max(0, N - 9);
      ang = -readv(w, po + 0, isf32) * (float)lo;
    } else if (t < 259) {
      int g = t - 253;
      float f0, f1, f3, fd;
      gate_fs(w, isf32, l, half, g, f0, f1, f3, fd);
      ang = fd;
    } else if (t == 259) {
      ang = -readv(w, po + 0, isf32);
    } else {
      int id = t - 260; int m = id / 10, q = id % 10;
      if (half) {
        float kap = readv(w, l*WSTRIDE + 44 + m, isf32);
        float pd  = readv(w, l*WSTRIDE + 40 + m, isf32);
        ang = kap * (float)(q*q) + pd * (float)q;
      }
    }
    float sn, cs; sincosf(ang, &sn, &cs);
    lb[t] = make_float2(cs, sn);
  } else if (t < LUT_PAD) {
    lb[t] = make_float2(1.f, 0.f);     // pad entries: identity (never used)
  }
}

#define LOADQ(DST, P) do { _Pragma("unroll") \
  for (int q_ = 0; q_ < 5; ++q_) DST[q_] = Uq[(P)*5 + q_]; } while (0)

// two output rows (R0, R0+1) from a 5-quad REAL row-pair, with fused rotation
#define BS_PAIR(UA, R0)                                                        \
  {                                                                            \
    float2 a0 = make_float2(0.f,0.f), a1 = make_float2(0.f,0.f);               \
    _Pragma("unroll")                                                          \
    for (int j = 0; j < 5; ++j) if (2*j < sd) {                                \
      const float2 m0 = (j==0)?loF(UA[0]):(j==1)?hiF(UA[0]):(j==2)?loF(UA[1])  \
                        :(j==3)?hiF(UA[1]):loF(UA[2]);                         \
      const float2 m1 = (j==0)?hiF(UA[2]):(j==1)?loF(UA[3]):(j==2)?hiF(UA[3])  \
                        :(j==3)?loF(UA[4]):hiF(UA[4]);                         \
      rmacL(a0, m0, v[2*j]); rmacH(a0, m0, v[2*j+1]);                          \
      rmacL(a1, m1, v[2*j]); rmacH(a1, m1, v[2*j+1]);                          \
    }                                                                          \
    a0 = cmul(a0, rot); rot = cmul(rot, step);                                 \
    base[(R0)*se] = a0;                                                        \
    if ((R0) + 1 < sd) {                                                       \
      a1 = cmul(a1, rot); rot = cmul(rot, step);                               \
      base[((R0)+1)*se] = a1;                                                  \
    }                                                                          \
  }

// ---- one BS chunk: REAL d x d block matvec + fused diagonal rotation ----
template<int sI, int sJ, int sA, int sB, bool INROT>
__device__ __forceinline__ void bs_chunk(
    float2* st, const float* __restrict__ U, int sd,
    int hi10, int lo10, int lo, int N,
    float2 rot, float2 step, float2 ir, float2 istep)
{
  constexpr int se = sI - sJ;
  float2* base = st + hi10*sA + lo10*sB + lo*sI + (N - lo)*sJ;
  float2 v[10];
#pragma unroll
  for (int k = 0; k < 10; ++k) {
    if (k < sd) {
      float2 tv = base[k*se];
      if (INROT) { tv = cmul(tv, ir); ir = cmul(ir, istep); }
      v[k] = tv;
    } else {
      v[k] = make_float2(0.f, 0.f);   // zero-fill so unguarded MAC halves are safe
    }
  }
  const float4* Uq = (const float4*)U;   // row-pair p -> quads [p*5 .. p*5+4]
  float4 ua[5], ub[5];
  LOADQ(ua, 0);
#pragma unroll
  for (int p = 0; p < 5; p += 2) {
    if (2*p < sd) {
      if (2*p + 2 < sd) LOADQ(ub, p + 1);
      BS_PAIR(ua, 2*p);
    }
    if (2*p + 2 < sd) {
      if (2*p + 4 < sd) LOADQ(ua, p + 2);
      BS_PAIR(ub, 2*p + 2);
    }
  }
}

template<int sI, int sJ, int sA, int sB, bool INROT>
__device__ __forceinline__ void bs_gate(
    float2* st, const float* __restrict__ Ub, const float2* __restrict__ L,
    int g, int lane, int ch0, int ch1, int ch2)
{
  const float2 step  = L[LUT_S + g];
  const float2 istep = INROT ? L[LUT_IS] : make_float2(1.f, 0.f);
#pragma unroll
  for (int r = 0; r < 3; ++r) {
    const int c = (r == 0) ? ch0 : (r == 1) ? ch1 : ch2;
    if (c >= 0) {
      int N = c >> 1;
      int spec = ((c & 1) << 6) + lane;
      if (spec < 100) {
        int lo = max(0, N - 9);
        const int sd = __builtin_amdgcn_readfirstlane(min(9, N) - lo + 1);
        int hi10 = spec / 10, lo10 = spec % 10;
        float2 rot = cmul(cmul(L[LUT_A + g*10 + hi10], L[LUT_B + g*10 + lo10]),
                          L[LUT_C + g*19 + N]);
        float2 ir = INROT ? L[LUT_I + N] : make_float2(1.f, 0.f);
        bs_chunk<sI,sJ,sA,sB,INROT>(st, Ub + N*100, sd, hi10, lo10, lo, N,
                                    rot, step, ir, istep);
      }
    }
  }
}

#define SM_PAIR(UA, R0)                                                        \
  {                                                                            \
    float2 a0 = make_float2(0.f,0.f), a1 = make_float2(0.f,0.f);               \
    _Pragma("unroll")                                                          \
    for (int j = 0; j < 5; ++j) {                                              \
      const float2 m0 = (j==0)?loF(UA[0]):(j==1)?hiF(UA[0]):(j==2)?loF(UA[1])  \
                        :(j==3)?hiF(UA[1]):loF(UA[2]);                         \
      const float2 m1 = (j==0)?hiF(UA[2]):(j==1)?loF(UA[3]):(j==2)?hiF(UA[3])  \
                        :(j==3)?loF(UA[4]):hiF(UA[4]);                         \
      rmacL(a0, m0, v[2*j]); rmacH(a0, m0, v[2*j+1]);                          \
      rmacL(a1, m1, v[2*j]); rmacH(a1, m1, v[2*j+1]);                          \
    }                                                                          \
    if (KERR) {                                                                \
      a0 = cmul(a0, cmul(kb, L[LUT_K + 30 + (R0)]));                           \
      a1 = cmul(a1, cmul(kb, L[LUT_K + 30 + (R0) + 1]));                       \
    }                                                                          \
    base[(R0)*sM]   = a0;                                                      \
    base[((R0)+1)*sM] = a1;                                                    \
  }

// ---- single-mode gate: REAL 10x10 matvec, optional fused Kerr+phd rotation ----
template<int sM, int pA, int pB, int pC, bool KERR>
__device__ __forceinline__ void sm_gate(
    float2* st, const float* __restrict__ U, const float2* __restrict__ L,
    bool smv, int q0, int q1, int q2)
{
  if (!smv) return;
  float2* base = st + q0*pA + q1*pB + q2*pC;
  float2 kb = make_float2(1.f, 0.f);
  if (KERR) kb = cmul(cmul(L[LUT_K + q0], L[LUT_K + 10 + q1]),
                      L[LUT_K + 20 + q2]);
  float2 v[10];
#pragma unroll
  for (int k = 0; k < 10; ++k) v[k] = base[k*sM];
  const float4* Uq = (const float4*)U;
  float4 ua[5], ub[5];
  LOADQ(ua, 0);
#pragma unroll
  for (int p = 0; p < 5; p += 2) {
    {
      if (p < 4) LOADQ(ub, p + 1);
      SM_PAIR(ua, 2*p);
    }
    if (p + 1 < 5) {
      if (p + 2 < 5) LOADQ(ua, p + 2);
      SM_PAIR(ub, 2*(p + 1));
    }
  }
}

// ------------------- K3: fused circuit — one block per batch, state in LDS -------------------
// LDS: state 104.5K + smU 12.8K + bsU(dbuf) 15.2K + luts 20.5K + misc ~0.6K = ~153.6K < 160K.
// __launch_bounds__(1024, 4) exactly as the proven R5 config (64-VGPR operating point).
__global__ __launch_bounds__(1024, 4)
void fused_circuit(
    const float* __restrict__ rslots, const float2* __restrict__ s0,
    const float2* __restrict__ lutg, float* __restrict__ out)
{
  __shared__ float2 st[ST_PHYS];                 // ~104.5 KB bank-uniform state
  __shared__ __align__(16) float smU[3200];      // all 32 single-mode REAL U's
  __shared__ __align__(16) float bsU[2*1900];    // double-buffered REAL BS gate
  __shared__ __align__(16) float2 lut[8][LUT_PAD];  // all 8 halves' rotation LUTs
  __shared__ float2 psi[4][10];
  __shared__ float redw[64];
  const int b = blockIdx.x, t = threadIdx.x;
  const int wv = t >> 6, lane = t & 63;

  const int wvu = __builtin_amdgcn_readfirstlane(wv);
  const int ch0 = __builtin_amdgcn_readfirstlane((int)g_perm[wvu][0]);
  const int ch1 = __builtin_amdgcn_readfirstlane((int)g_perm[wvu][1]);
  const int ch2 = __builtin_amdgcn_readfirstlane((int)g_perm[wvu][2]);
  const bool smv = (t < 1000);
  const int q0 = t / 100, q1 = (t / 10) % 10, q2 = t % 10;

  // ---- initial product state (Dm real @ complex S0 column 0) + staging ----
  if (t < 40) {
    int m = t / 10, r = t % 10;
    const float* Dmr = rslots + (size_t)(R_DM + b*4 + m) * 100;
    float2 acc = make_float2(0.f, 0.f);
    for (int c = 0; c < 10; ++c) {
      float a = Dmr[r*10 + c];
      float2 vv = s0[c * 10];   // S0 column 0
      acc.x += a * vv.x;
      acc.y += a * vv.y;
    }
    psi[m][r] = acc;
  }
  for (int i = t; i < 800; i += 1024)           // smU: 3200 floats = 800 quads
    ((float4*)smU)[i] = ((const float4*)(rslots + (size_t)R_SQ * 100))[i];
  for (int i = t; i < 475; i += 1024)           // bsU gate 0: 1900 floats = 475 quads
    ((float4*)bsU)[i] = ((const float4*)(rslots + (size_t)R_BS * 100))[i];
  for (int i = t; i < 8 * LUT_PAD / 2; i += 1024)  // LUTs: 2560 float2 = 1280 quads
    ((float4*)lut)[i] = ((const float4*)lutg)[i];
  __syncthreads();
  for (int e = t; e < 10000; e += 1024) {
    int ph = phys_of(e);
    float2 z  = psi[0][e/1000];
    float2 w1 = psi[1][(e/100)%10];
    float2 r1 = make_float2(z.x*w1.x - z.y*w1.y, z.x*w1.y + z.y*w1.x);
    float2 w2 = psi[2][(e/10)%10];
    float2 r2 = make_float2(r1.x*w2.x - r1.y*w2.y, r1.x*w2.y + r1.y*w2.x);
    float2 w3 = psi[3][e%10];
    st[ph] = make_float2(r2.x*w3.x - r2.y*w3.y, r2.x*w3.y + r2.y*w3.x);
  }
  __syncthreads();

  // split prefetch: global->reg at gate start, reg->LDS after compute.
  float4 pf;
  auto pf_load = [&](int next) {
    if (next < 48 && t < 475)
      pf = ((const float4*)(rslots + (size_t)(R_BS + next*19) * 100))[t];
  };
  auto pf_store = [&](int next) {
    if (next < 48 && t < 475)
      ((float4*)(bsU + (next & 1) * 1900))[t] = pf;
  };

  // ---- circuit ----
#pragma unroll 1
  for (int l = 0; l < NLAYERS; ++l) {
#pragma unroll 1
    for (int half = 0; half < 2; ++half) {
      const int g6 = l*12 + half*6;
      const float2* L = lut[(l << 1) | half];

      pf_load(g6+1);
      bs_gate<F0,F1,F2,F3,true >(st, bsU+((g6+0)&1)*1900, L, 0, lane, ch0,ch1,ch2);
      pf_store(g6+1);
      __syncthreads();
      pf_load(g6+2);
      bs_gate<F0,F2,F1,F3,false>(st, bsU+((g6+1)&1)*1900, L, 1, lane, ch0,ch1,ch2);
      pf_store(g6+2);
      __syncthreads();
      pf_load(g6+3);
      bs_gate<F0,F3,F1,F2,false>(st, bsU+((g6+2)&1)*1900, L, 2, lane, ch0,ch1,ch2);
      pf_store(g6+3);
      __syncthreads();
      pf_load(g6+4);
      bs_gate<F1,F2,F0,F3,false>(st, bsU+((g6+3)&1)*1900, L, 3, lane, ch0,ch1,ch2);
      pf_store(g6+4);
      __syncthreads();
      pf_load(g6+5);
      bs_gate<F1,F3,F0,F2,false>(st, bsU+((g6+4)&1)*1900, L, 4, lane, ch0,ch1,ch2);
      pf_store(g6+5);
      __syncthreads();
      pf_load(g6+6);
      bs_gate<F2,F3,F0,F1,false>(st, bsU+((g6+5)&1)*1900, L, 5, lane, ch0,ch1,ch2);
      pf_store(g6+6);
      __syncthreads();

      const int ub_ = (half == 0) ? (l*4) : (16 + l*4);
      sm_gate<F0,F1,F2,F3,false>(st, smU+(ub_+0)*100, L, smv, q0,q1,q2);
      __syncthreads();
      sm_gate<F1,F0,F2,F3,false>(st, smU+(ub_+1)*100, L, smv, q0,q1,q2);
      __syncthreads();
      sm_gate<F2,F0,F1,F3,false>(st, smU+(ub_+2)*100, L, smv, q0,q1,q2);
      __syncthreads();
      if (half)
        sm_gate<F3,F0,F1,F2,true >(st, smU+(ub_+3)*100, L, smv, q0,q1,q2);
      else
        sm_gate<F3,F0,F1,F2,false>(st, smU+(ub_+3)*100, L, smv, q0,q1,q2);
      __syncthreads();
    }
  }

  // ---- photon-number expectations (wave shuffle reduce) ----
  float a0 = 0.f, a1 = 0.f, a2 = 0.f, a3 = 0.f;
  for (int e = t; e < 10000; e += 1024) {
    int ph = phys_of(e);
    float2 z = st[ph];
    float pz = z.x*z.x + z.y*z.y;
    a0 += pz * (float)(e/1000);
    a1 += pz * (float)((e/100)%10);
    a2 += pz * (float)((e/10)%10);
    a3 += pz * (float)(e%10);
  }
  for (int off2 = 32; off2 > 0; off2 >>= 1) {
    a0 += __shfl_down(a0, off2, 64);
    a1 += __shfl_down(a1, off2, 64);
    a2 += __shfl_down(a2, off2, 64);
    a3 += __shfl_down(a3, off2, 64);
  }
  if (lane == 0) {
    redw[wv*4+0] = a0; redw[wv*4+1] = a1;
    redw[wv*4+2] = a2; redw[wv*4+3] = a3;
  }
  __syncthreads();
  if (t < 4) {
    float s = 0.f;
    for (int ww = 0; ww < 16; ++ww) s += redw[ww*4 + t];
    out[b*4 + t] = s;
  }
}

extern "C" void kernel_launch(void* const* d_in, const int* in_sizes, int n_in,
                              void* d_out, int out_size, void* d_ws, size_t ws_size,
                              hipStream_t stream) {
  const void* inp = d_in[0];
  const void* w   = d_in[1];
  float* out = (float*)d_out;                 // reference output dtype is float32
  int*    flag   = (int*)d_ws;                // 16-byte header
  float2* s0     = (float2*)((char*)d_ws + 16);          // complex S0 (100 float2)
  float*  rslots = (float*)((char*)d_ws + 1024);         // 1968 real 10x10 slots
  float2* lutg   = (float2*)((char*)d_ws + 1024 + NRSLOTS*400);  // 8 x 320 float2

  sniff_dtype<<<dim3(1), dim3(256), 0, stream>>>(inp, in_sizes[0], flag);
  build_gens<<<dim3(NRSLOTS + 1), dim3(128), 0, stream>>>(rslots, s0, inp, w, flag);
  build_luts<<<dim3(8), dim3(LUT_PAD), 0, stream>>>(lutg, w, flag);
  expm_real<<<dim3(NRSLOTS), dim3(128), 0, stream>>>(rslots);
  expm_cplx<<<dim3(1), dim3(128), 0, stream>>>(s0);
  fused_circuit<<<dim3(NB), dim3(1024), 0, stream>>>(rslots, s0, lutg, out);
}

// Round 8
// 323.977 us; speedup vs baseline: 1.6022x; 1.0421x over previous
//
#include <hip/hip_runtime.h>
#include <hip/hip_bf16.h>

#define CUT 10
#define NB 256
#define NLAYERS 4
#define WSTRIDE 48

// real slot map (each real slot = 10x10 float, 100 floats)
#define R_DM 0        // 1024 input-displacement matrices (real)
#define R_SQ 1024     // 16 squeezers (l*4+m) (real)
#define R_DS 1040     // 16 displacement radial parts (l*4+m) (real)
#define R_BS 1056     // 48 gates * 19 photon-number blocks (real)
#define NRSLOTS 1968  // real slots; +1 extra build block for complex S0

// physical (bank-swizzled) per-mode strides: ph = 1110*n0 + 111*n1 + 11*n2 + n3
// (R7's "bank-uniform" (1307,131,13,1) variant INCREASED conflicts 15% — reverted.)
#define F0 1110
#define F1 111
#define F2 11
#define F3 1
#define ST_PHYS 11100

// rotation LUT layout (float2 entries = e^{i*ang})
#define LUT_A  0     // [6][10] e^{i f0_g * h}
#define LUT_B  60    // [6][10] e^{i f1_g * l}
#define LUT_C  120   // [6][19] e^{i (f3_g N + fdc_g lo(N))}
#define LUT_I  234   // [19]    e^{-i phi1 lo(N)}   (gate-0 input rot start)
#define LUT_S  253   // [6]     e^{i fdc_g}         (row step)
#define LUT_IS 259   // [1]     e^{-i phi1}         (input rot step)
#define LUT_K  260   // [4][10] e^{i (kap_m q^2 + phd_m q)}
#define LUT_N  300
#define LUT_PAD 320

typedef __hip_bfloat16 bf16;

// read element i of a buffer whose dtype (f32 vs bf16) was sniffed at runtime
__device__ __forceinline__ float readv(const void* p, int i, int isf32) {
  if (isf32) return ((const float*)p)[i];
  return __bfloat162float(((const bf16*)p)[i]);
}

// real MAC: acc += m * v (complex v, real m), m = mm.x (rmacL) or mm.y (rmacH)
// -> ONE v_pk_fma_f32 per complex MAC (the real-algebra payoff)
__device__ __forceinline__ void rmacL(float2& a, float2 mm, float2 v) {
  asm("v_pk_fma_f32 %0, %1, %2, %0 op_sel:[0,0,0] op_sel_hi:[0,1,1]"
      : "+v"(a) : "v"(mm), "v"(v));
}
__device__ __forceinline__ void rmacH(float2& a, float2 mm, float2 v) {
  asm("v_pk_fma_f32 %0, %1, %2, %0 op_sel:[1,0,0] op_sel_hi:[1,1,1]"
      : "+v"(a) : "v"(mm), "v"(v));
}

// full complex multiply d = u*v : 2 packed ops
__device__ __forceinline__ float2 cmul(float2 u, float2 v) {
  float2 d;
  asm("v_pk_mul_f32 %0, %1, %2 op_sel:[0,0] op_sel_hi:[0,1]\n\t"
      "v_pk_fma_f32 %0, %1, %2, %0 op_sel:[1,1,0] op_sel_hi:[1,0,1] neg_lo:[1,0,0]"
      : "=&v"(d) : "v"(u), "v"(v));
  return d;
}

__device__ __forceinline__ float2 loF(const float4& q) { return make_float2(q.x, q.y); }
__device__ __forceinline__ float2 hiF(const float4& q) { return make_float2(q.z, q.w); }

// chunk permutation: wave w handles chunks g_perm[w][0..2]; chunk c: N=c/2,
// spec offset (c&1)*64. Balanced so per-wave sum(d^2) is ~84 (range 76..100).
__device__ const signed char g_perm[16][3] = {
  {18,-1,-1},{19,-1,-1},{16, 0,-1},{17, 1,-1},{20,36,-1},{21,37,-1},
  {14, 6,34},{15, 7,35},{22,30,-1},{23,31,-1},{12, 8, 4},{13, 9, 5},
  {24,28,32},{25,29,33},{10,26, 2},{11,27, 3}
};

// per-gate fused output-rotation coefficients (diagonal phases merged across gates):
//   angle(row) = f0*hi10 + f1*lo10 + f3*N + fdc*(lo+row)
__device__ __forceinline__ void gate_fs(const void* w, int isf32, int l, int half,
                                        int g, float& f0, float& f1, float& f3,
                                        float& fdc) {
  int po = l*WSTRIDE + (half ? 26 : 6);   // phases ph1/ph2
  int vo = l*WSTRIDE + (half ? 32 : 12);  // vphases vp1/vp2
  f0 = 0.f; f1 = 0.f; f3 = 0.f;
  switch (g) {
    case 0: fdc = readv(w, po+0, isf32) - readv(w, po+1, isf32); break;
    case 1: fdc = readv(w, po+1, isf32) - readv(w, po+2, isf32); break;
    case 2: f0 = -readv(w, po+3, isf32); fdc = readv(w, po+2, isf32); break;
    case 3: fdc = readv(w, po+3, isf32) - readv(w, po+4, isf32); break;
    case 4: f1 = -readv(w, po+5, isf32); fdc = readv(w, po+4, isf32); break;
    default: {
      float vp0 = readv(w, vo+0, isf32), vp1 = readv(w, vo+1, isf32);
      float vp2 = readv(w, vo+2, isf32), vp3 = readv(w, vo+3, isf32);
      if (half) {   // absorb displacement pre-phases e^{-i phd n}
        vp0 -= readv(w, l*WSTRIDE+40+0, isf32);
        vp1 -= readv(w, l*WSTRIDE+40+1, isf32);
        vp2 -= readv(w, l*WSTRIDE+40+2, isf32);
        vp3 -= readv(w, l*WSTRIDE+40+3, isf32);
      }
      f0 = vp0; f1 = vp1; f3 = vp3;
      fdc = vp2 + readv(w, po+5, isf32) - vp3;
    }
  }
}

// ------------------- K1: prep — local dtype sniff + ALL generators + LUTs -------------------
// blocks 0..1967: real generators; 1968: complex S0 generator; 1969..1976: rotation LUTs.
// Each block sniffs the (tiny, L2-hot) input locally -> no separate sniff kernel/launch.
__global__ void prep(float* rslots, float2* s0, float2* lutg,
                     const void* inp, const void* w, int n_elems) {
  __shared__ float wred[5];
  __shared__ int sflag;
  const int bid = blockIdx.x, t = threadIdx.x;
  const int wv = t >> 6, lane = t & 63;

  // ---- local dtype sniff ----
  {
    const unsigned short* h = (const unsigned short*)inp;
    float mx = 0.f;
    for (int i = t; i < n_elems; i += 320) {
      unsigned short u = h[i];
      bf16 bv = *(const bf16*)&u;
      float v = fabsf(__bfloat162float(bv));
      if (!(v < 1e30f)) v = 1e30f;
      mx = fmaxf(mx, v);
    }
    for (int off = 32; off > 0; off >>= 1)
      mx = fmaxf(mx, __shfl_down(mx, off, 64));
    if (lane == 0) wred[wv] = mx;
    __syncthreads();
    if (t == 0) {
      float m2 = wred[0];
      for (int i2 = 1; i2 < 5; ++i2) m2 = fmaxf(m2, wred[i2]);
      sflag = (m2 > 1000.f) ? 1 : 0;   // 1 => buffer is really f32
    }
    __syncthreads();
  }
  const int isf32 = sflag;

  if (bid <= NRSLOTS) {               // ---- generators ----
    if (t >= 100) return;
    int i = t / 10, j = t % 10;
    if (bid == NRSLOTS) {             // complex S0 generator
      float2 val = make_float2(0.f, 0.f);
      if (j == i + 2)      { float c = sqrtf((float)((i+1)*(i+2))); val.y = -0.25f*c; }
      else if (i == j + 2) { float c = sqrtf((float)((j+1)*(j+2))); val.y = -0.25f*c; }
      s0[t] = val;
      return;
    }
    const int s = bid;
    float val = 0.f;
    if (s < R_SQ) {                   // input displacement, real: r(adag - a)
      float r = readv(inp, s, isf32);
      if (i == j + 1)      val =  r * sqrtf((float)(j+1));
      else if (j == i + 1) val = -r * sqrtf((float)(i+1));
    } else if (s < R_DS) {            // squeezer, real: 0.5 r (a^2 - adag^2)
      int k = s - R_SQ; int l = k >> 2; int m = k & 3;
      float r = readv(w, l*WSTRIDE + 16 + m, isf32);
      if (j == i + 2)      val =  0.5f*r*sqrtf((float)((i+1)*(i+2)));
      else if (i == j + 2) val = -0.5f*r*sqrtf((float)((j+1)*(j+2)));
    } else if (s < R_BS) {            // displacement radial part, real: rd(adag - a)
      int k = s - R_DS; int l = k >> 2; int m = k & 3;
      float rd = readv(w, l*WSTRIDE + 36 + m, isf32);
      if (i == j + 1)      val =  rd * sqrtf((float)(j+1));
      else if (j == i + 1) val = -rd * sqrtf((float)(i+1));
    } else {                          // BS block, real part (phase conjugated out)
      int rel = s - R_BS;
      int g = rel / 19; int N = rel % 19;
      int l = g / 12; int hf = (g % 12) / 6; int p = g % 6;
      float th = readv(w, l*WSTRIDE + (hf ? 20 : 0) + p, isf32);
      int lo = max(0, N - 9), hi = min(9, N);
      int d = hi - lo + 1;
      if (i < d && j < d) {
        if (i == j + 1)      val =  th * sqrtf((float)((lo + j + 1) * (N - lo - j)));
        else if (j == i + 1) val = -th * sqrtf((float)((lo + i + 1) * (N - lo - i)));
      }
    }
    rslots[(size_t)s * 100 + t] = val;
  } else {                            // ---- rotation LUTs (8 halves) ----
    const int h = bid - NRSLOTS - 1;  // 0..7 = l*2 + half
    const int l = h >> 1, half = h & 1;
    const int po = l*WSTRIDE + (half ? 26 : 6);
    float2* lb = lutg + (size_t)h * LUT_PAD;
    if (t < LUT_N) {
      float ang = 0.f;
      if (t < 120) {
        int isB = (t >= 60);
        int id = isB ? t - 60 : t;
        int g = id / 10, q = id % 10;
        float f0, f1, f3, fd;
        gate_fs(w, isf32, l, half, g, f0, f1, f3, fd);
        ang = (isB ? f1 : f0) * (float)q;
      } else if (t < 234) {
        int id = t - 120; int g = id / 19, N = id % 19;
        float f0, f1, f3, fd;
        gate_fs(w, isf32, l, half, g, f0, f1, f3, fd);
        int lo = max(0, N - 9);
        ang = f3 * (float)N + fd * (float)lo;
      } else if (t < 253) {
        int N = t - 234; int lo = max(0, N - 9);
        ang = -readv(w, po + 0, isf32) * (float)lo;
      } else if (t < 259) {
        int g = t - 253;
        float f0, f1, f3, fd;
        gate_fs(w, isf32, l, half, g, f0, f1, f3, fd);
        ang = fd;
      } else if (t == 259) {
        ang = -readv(w, po + 0, isf32);
      } else {
        int id = t - 260; int m = id / 10, q = id % 10;
        if (half) {
          float kap = readv(w, l*WSTRIDE + 44 + m, isf32);
          float pd  = readv(w, l*WSTRIDE + 40 + m, isf32);
          ang = kap * (float)(q*q) + pd * (float)q;
        }
      }
      float sn, cs; sincosf(ang, &sn, &cs);
      lb[t] = make_float2(cs, sn);
    } else if (t < LUT_PAD) {
      lb[t] = make_float2(1.f, 0.f);  // pad entries: identity (never used)
    }
  }
}

// ------------------- K2: expm — real slots (blocks 0..1967) + complex S0 (block 1968) ------
__global__ void expm_all2(float* rslots, float2* s0) {
  __shared__ float Tr[100], Pr[100], Rr[100];
  __shared__ float2 Tc[100], Pc[100], Rc[100];
  __shared__ float rowsum[10];
  __shared__ int sshift;
  const int bid = blockIdx.x, t = threadIdx.x;
  const int i = t / 10, j = t % 10;
  if (bid < NRSLOTS) {
    float* G = rslots + (size_t)bid * 100;
    if (t < 100) Tr[t] = G[t];
    __syncthreads();
    if (t < 10) {
      float sum = 0.f;
      for (int c = 0; c < 10; ++c) sum += fabsf(Tr[t*10+c]);
      rowsum[t] = sum;
    }
    __syncthreads();
    if (t == 0) {
      float nm = 0.f;
      for (int r = 0; r < 10; ++r) nm = fmaxf(nm, rowsum[r]);
      int sc = 0;
      if (!(nm < 1e6f)) sc = 0;
      else if (nm > 0.25f) sc = (int)ceilf(log2f(nm * 4.f));
      sshift = min(max(sc, 0), 40);
    }
    __syncthreads();
    int sh = sshift;
    float scl = ldexpf(1.f, -sh);
    if (t < 100) {
      float z = Tr[t] * scl;
      Tr[t] = z; Pr[t] = z;
      Rr[t] = z + (i == j ? 1.f : 0.f);
    }
    __syncthreads();
    for (int k = 2; k <= 12; ++k) {
      float acc = 0.f;
      if (t < 100) {
        for (int c = 0; c < 10; ++c) acc += Pr[i*10+c] * Tr[c*10+j];
        acc *= 1.f / (float)k;
      }
      __syncthreads();
      if (t < 100) { Pr[t] = acc; Rr[t] += acc; }
      __syncthreads();
    }
    for (int q = 0; q < sh; ++q) {
      float acc = 0.f;
      if (t < 100) {
        for (int c = 0; c < 10; ++c) acc += Rr[i*10+c] * Rr[c*10+j];
      }
      __syncthreads();
      if (t < 100) Rr[t] = acc;
      __syncthreads();
    }
    if (t < 100) G[t] = Rr[t];
  } else {
    float2* G = s0;
    if (t < 100) Tc[t] = G[t];
    __syncthreads();
    if (t < 10) {
      float sum = 0.f;
      for (int c = 0; c < 10; ++c) { float2 z = Tc[t*10+c]; sum += fabsf(z.x) + fabsf(z.y); }
      rowsum[t] = sum;
    }
    __syncthreads();
    if (t == 0) {
      float nm = 0.f;
      for (int r = 0; r < 10; ++r) nm = fmaxf(nm, rowsum[r]);
      int sc = 0;
      if (!(nm < 1e6f)) sc = 0;
      else if (nm > 0.25f) sc = (int)ceilf(log2f(nm * 4.f));
      sshift = min(max(sc, 0), 40);
    }
    __syncthreads();
    int sh = sshift;
    float scl = ldexpf(1.f, -sh);
    if (t < 100) {
      float2 z = Tc[t]; z.x *= scl; z.y *= scl;
      Tc[t] = z; Pc[t] = z;
      Rc[t] = make_float2(z.x + (i == j ? 1.f : 0.f), z.y);
    }
    __syncthreads();
    for (int k = 2; k <= 12; ++k) {
      float2 acc = make_float2(0.f, 0.f);
      if (t < 100) {
        for (int c = 0; c < 10; ++c) {
          float2 a = Pc[i*10+c], b = Tc[c*10+j];
          acc.x += a.x*b.x - a.y*b.y;
          acc.y += a.x*b.y + a.y*b.x;
        }
        float inv = 1.f / (float)k;
        acc.x *= inv; acc.y *= inv;
      }
      __syncthreads();
      if (t < 100) { Pc[t] = acc; Rc[t].x += acc.x; Rc[t].y += acc.y; }
      __syncthreads();
    }
    for (int q = 0; q < sh; ++q) {
      float2 acc = make_float2(0.f, 0.f);
      if (t < 100) {
        for (int c = 0; c < 10; ++c) {
          float2 a = Rc[i*10+c], b = Rc[c*10+j];
          acc.x += a.x*b.x - a.y*b.y;
          acc.y += a.x*b.y + a.y*b.x;
        }
      }
      __syncthreads();
      if (t < 100) Rc[t] = acc;
      __syncthreads();
    }
    if (t < 100) G[t] = Rc[t];
  }
}

#define LOADQ(DST, P) do { _Pragma("unroll") \
  for (int q_ = 0; q_ < 5; ++q_) DST[q_] = Uq[(P)*5 + q_]; } while (0)

// two output rows (R0, R0+1) from a 5-quad REAL row-pair, with fused rotation
#define BS_PAIR(UA, R0)                                                        \
  {                                                                            \
    float2 a0 = make_float2(0.f,0.f), a1 = make_float2(0.f,0.f);               \
    _Pragma("unroll")                                                          \
    for (int j = 0; j < 5; ++j) if (2*j < sd) {                                \
      const float2 m0 = (j==0)?loF(UA[0]):(j==1)?hiF(UA[0]):(j==2)?loF(UA[1])  \
                        :(j==3)?hiF(UA[1]):loF(UA[2]);                         \
      const float2 m1 = (j==0)?hiF(UA[2]):(j==1)?loF(UA[3]):(j==2)?hiF(UA[3])  \
                        :(j==3)?loF(UA[4]):hiF(UA[4]);                         \
      rmacL(a0, m0, v[2*j]); rmacH(a0, m0, v[2*j+1]);                          \
      rmacL(a1, m1, v[2*j]); rmacH(a1, m1, v[2*j+1]);                          \
    }                                                                          \
    a0 = cmul(a0, rot); rot = cmul(rot, step);                                 \
    base[(R0)*se] = a0;                                                        \
    if ((R0) + 1 < sd) {                                                       \
      a1 = cmul(a1, rot); rot = cmul(rot, step);                               \
      base[((R0)+1)*se] = a1;                                                  \
    }                                                                          \
  }

// ---- one BS chunk: REAL d x d block matvec + fused diagonal rotation ----
template<int sI, int sJ, int sA, int sB, bool INROT>
__device__ __forceinline__ void bs_chunk(
    float2* st, const float* __restrict__ U, int sd,
    int hi10, int lo10, int lo, int N,
    float2 rot, float2 step, float2 ir, float2 istep)
{
  constexpr int se = sI - sJ;
  float2* base = st + hi10*sA + lo10*sB + lo*sI + (N - lo)*sJ;
  float2 v[10];
#pragma unroll
  for (int k = 0; k < 10; ++k) {
    if (k < sd) {
      float2 tv = base[k*se];
      if (INROT) { tv = cmul(tv, ir); ir = cmul(ir, istep); }
      v[k] = tv;
    } else {
      v[k] = make_float2(0.f, 0.f);   // zero-fill so unguarded MAC halves are safe
    }
  }
  const float4* Uq = (const float4*)U;   // row-pair p -> quads [p*5 .. p*5+4]
  float4 ua[5], ub[5];
  LOADQ(ua, 0);
#pragma unroll
  for (int p = 0; p < 5; p += 2) {
    if (2*p < sd) {
      if (2*p + 2 < sd) LOADQ(ub, p + 1);
      BS_PAIR(ua, 2*p);
    }
    if (2*p + 2 < sd) {
      if (2*p + 4 < sd) LOADQ(ua, p + 2);
      BS_PAIR(ub, 2*p + 2);
    }
  }
}

template<int sI, int sJ, int sA, int sB, bool INROT>
__device__ __forceinline__ void bs_gate(
    float2* st, const float* __restrict__ Ub, const float2* __restrict__ L,
    int g, int lane, int ch0, int ch1, int ch2)
{
  const float2 step  = L[LUT_S + g];
  const float2 istep = INROT ? L[LUT_IS] : make_float2(1.f, 0.f);
#pragma unroll
  for (int r = 0; r < 3; ++r) {
    const int c = (r == 0) ? ch0 : (r == 1) ? ch1 : ch2;
    if (c >= 0) {
      int N = c >> 1;
      int spec = ((c & 1) << 6) + lane;
      if (spec < 100) {
        int lo = max(0, N - 9);
        const int sd = __builtin_amdgcn_readfirstlane(min(9, N) - lo + 1);
        int hi10 = spec / 10, lo10 = spec % 10;
        float2 rot = cmul(cmul(L[LUT_A + g*10 + hi10], L[LUT_B + g*10 + lo10]),
                          L[LUT_C + g*19 + N]);
        float2 ir = INROT ? L[LUT_I + N] : make_float2(1.f, 0.f);
        bs_chunk<sI,sJ,sA,sB,INROT>(st, Ub + N*100, sd, hi10, lo10, lo, N,
                                    rot, step, ir, istep);
      }
    }
  }
}

#define SM_PAIR(UA, R0)                                                        \
  {                                                                            \
    float2 a0 = make_float2(0.f,0.f), a1 = make_float2(0.f,0.f);               \
    _Pragma("unroll")                                                          \
    for (int j = 0; j < 5; ++j) {                                              \
      const float2 m0 = (j==0)?loF(UA[0]):(j==1)?hiF(UA[0]):(j==2)?loF(UA[1])  \
                        :(j==3)?hiF(UA[1]):loF(UA[2]);                         \
      const float2 m1 = (j==0)?hiF(UA[2]):(j==1)?loF(UA[3]):(j==2)?hiF(UA[3])  \
                        :(j==3)?loF(UA[4]):hiF(UA[4]);                         \
      rmacL(a0, m0, v[2*j]); rmacH(a0, m0, v[2*j+1]);                          \
      rmacL(a1, m1, v[2*j]); rmacH(a1, m1, v[2*j+1]);                          \
    }                                                                          \
    if (KERR) {                                                                \
      a0 = cmul(a0, cmul(kb, L[LUT_K + 30 + (R0)]));                           \
      a1 = cmul(a1, cmul(kb, L[LUT_K + 30 + (R0) + 1]));                       \
    }                                                                          \
    base[(R0)*sM]   = a0;                                                      \
    base[((R0)+1)*sM] = a1;                                                    \
  }

// ---- single-mode gate: REAL 10x10 matvec, optional fused Kerr+phd rotation ----
template<int sM, int pA, int pB, int pC, bool KERR>
__device__ __forceinline__ void sm_gate(
    float2* st, const float* __restrict__ U, const float2* __restrict__ L,
    bool smv, int q0, int q1, int q2)
{
  if (!smv) return;
  float2* base = st + q0*pA + q1*pB + q2*pC;
  float2 kb = make_float2(1.f, 0.f);
  if (KERR) kb = cmul(cmul(L[LUT_K + q0], L[LUT_K + 10 + q1]),
                      L[LUT_K + 20 + q2]);
  float2 v[10];
#pragma unroll
  for (int k = 0; k < 10; ++k) v[k] = base[k*sM];
  const float4* Uq = (const float4*)U;
  float4 ua[5], ub[5];
  LOADQ(ua, 0);
#pragma unroll
  for (int p = 0; p < 5; p += 2) {
    {
      if (p < 4) LOADQ(ub, p + 1);
      SM_PAIR(ua, 2*p);
    }
    if (p + 1 < 5) {
      if (p + 2 < 5) LOADQ(ua, p + 2);
      SM_PAIR(ub, 2*(p + 1));
    }
  }
}

// ------------------- K3: fused circuit — one block per batch, state in LDS -------------------
// LDS: state 88.8K + smU 12.8K + bsU(dbuf) 15.2K + luts(8 halves) 20.5K + misc
// ~0.6K = ~137.9K < 160K. All sincos hoisted to prep (runs once).
// __launch_bounds__(1024, 4): the proven R5 config (64-VGPR operating point).
__global__ __launch_bounds__(1024, 4)
void fused_circuit(
    const float* __restrict__ rslots, const float2* __restrict__ s0,
    const float2* __restrict__ lutg, float* __restrict__ out)
{
  __shared__ float2 st[ST_PHYS];                 // ~89 KB swizzled state
  __shared__ __align__(16) float smU[3200];      // all 32 single-mode REAL U's
  __shared__ __align__(16) float bsU[2*1900];    // double-buffered REAL BS gate
  __shared__ __align__(16) float2 lut[8][LUT_PAD];  // all 8 halves' rotation LUTs
  __shared__ float2 psi[4][10];
  __shared__ float redw[64];
  const int b = blockIdx.x, t = threadIdx.x;
  const int wv = t >> 6, lane = t & 63;

  const int wvu = __builtin_amdgcn_readfirstlane(wv);
  const int ch0 = __builtin_amdgcn_readfirstlane((int)g_perm[wvu][0]);
  const int ch1 = __builtin_amdgcn_readfirstlane((int)g_perm[wvu][1]);
  const int ch2 = __builtin_amdgcn_readfirstlane((int)g_perm[wvu][2]);
  const bool smv = (t < 1000);
  const int q0 = t / 100, q1 = (t / 10) % 10, q2 = t % 10;

  // ---- initial product state (Dm real @ complex S0 column 0) + staging ----
  if (t < 40) {
    int m = t / 10, r = t % 10;
    const float* Dmr = rslots + (size_t)(R_DM + b*4 + m) * 100;
    float2 acc = make_float2(0.f, 0.f);
    for (int c = 0; c < 10; ++c) {
      float a = Dmr[r*10 + c];
      float2 vv = s0[c * 10];   // S0 column 0
      acc.x += a * vv.x;
      acc.y += a * vv.y;
    }
    psi[m][r] = acc;
  }
  for (int i = t; i < 800; i += 1024)           // smU: 3200 floats = 800 quads
    ((float4*)smU)[i] = ((const float4*)(rslots + (size_t)R_SQ * 100))[i];
  for (int i = t; i < 475; i += 1024)           // bsU gate 0: 1900 floats = 475 quads
    ((float4*)bsU)[i] = ((const float4*)(rslots + (size_t)R_BS * 100))[i];
  for (int i = t; i < 8 * LUT_PAD / 2; i += 1024)  // LUTs: 2560 float2 = 1280 quads
    ((float4*)lut)[i] = ((const float4*)lutg)[i];
  __syncthreads();
  for (int e = t; e < 10000; e += 1024) {
    int ph = e + e/10 + e/100;
    float2 z  = psi[0][e/1000];
    float2 w1 = psi[1][(e/100)%10];
    float2 r1 = make_float2(z.x*w1.x - z.y*w1.y, z.x*w1.y + z.y*w1.x);
    float2 w2 = psi[2][(e/10)%10];
    float2 r2 = make_float2(r1.x*w2.x - r1.y*w2.y, r1.x*w2.y + r1.y*w2.x);
    float2 w3 = psi[3][e%10];
    st[ph] = make_float2(r2.x*w3.x - r2.y*w3.y, r2.x*w3.y + r2.y*w3.x);
  }
  __syncthreads();

  // split prefetch: global->reg at gate start, reg->LDS after compute.
  float4 pf;
  auto pf_load = [&](int next) {
    if (next < 48 && t < 475)
      pf = ((const float4*)(rslots + (size_t)(R_BS + next*19) * 100))[t];
  };
  auto pf_store = [&](int next) {
    if (next < 48 && t < 475)
      ((float4*)(bsU + (next & 1) * 1900))[t] = pf;
  };

  // ---- circuit ----
#pragma unroll 1
  for (int l = 0; l < NLAYERS; ++l) {
#pragma unroll 1
    for (int half = 0; half < 2; ++half) {
      const int g6 = l*12 + half*6;
      const float2* L = lut[(l << 1) | half];

      pf_load(g6+1);
      bs_gate<F0,F1,F2,F3,true >(st, bsU+((g6+0)&1)*1900, L, 0, lane, ch0,ch1,ch2);
      pf_store(g6+1);
      __syncthreads();
      pf_load(g6+2);
      bs_gate<F0,F2,F1,F3,false>(st, bsU+((g6+1)&1)*1900, L, 1, lane, ch0,ch1,ch2);
      pf_store(g6+2);
      __syncthreads();
      pf_load(g6+3);
      bs_gate<F0,F3,F1,F2,false>(st, bsU+((g6+2)&1)*1900, L, 2, lane, ch0,ch1,ch2);
      pf_store(g6+3);
      __syncthreads();
      pf_load(g6+4);
      bs_gate<F1,F2,F0,F3,false>(st, bsU+((g6+3)&1)*1900, L, 3, lane, ch0,ch1,ch2);
      pf_store(g6+4);
      __syncthreads();
      pf_load(g6+5);
      bs_gate<F1,F3,F0,F2,false>(st, bsU+((g6+4)&1)*1900, L, 4, lane, ch0,ch1,ch2);
      pf_store(g6+5);
      __syncthreads();
      pf_load(g6+6);
      bs_gate<F2,F3,F0,F1,false>(st, bsU+((g6+5)&1)*1900, L, 5, lane, ch0,ch1,ch2);
      pf_store(g6+6);
      __syncthreads();

      const int ub_ = (half == 0) ? (l*4) : (16 + l*4);
      sm_gate<F0,F1,F2,F3,false>(st, smU+(ub_+0)*100, L, smv, q0,q1,q2);
      __syncthreads();
      sm_gate<F1,F0,F2,F3,false>(st, smU+(ub_+1)*100, L, smv, q0,q1,q2);
      __syncthreads();
      sm_gate<F2,F0,F1,F3,false>(st, smU+(ub_+2)*100, L, smv, q0,q1,q2);
      __syncthreads();
      // Final half's Kerr/displacement phase diagonal is dead (only |.|^2 follows):
      // unit phases don't change probabilities -> skip KERR on (l==NLAYERS-1, half==1).
      if (half && l != NLAYERS - 1)
        sm_gate<F3,F0,F1,F2,true >(st, smU+(ub_+3)*100, L, smv, q0,q1,q2);
      else
        sm_gate<F3,F0,F1,F2,false>(st, smU+(ub_+3)*100, L, smv, q0,q1,q2);
      __syncthreads();
    }
  }

  // ---- photon-number expectations (wave shuffle reduce) ----
  float a0 = 0.f, a1 = 0.f, a2 = 0.f, a3 = 0.f;
  for (int e = t; e < 10000; e += 1024) {
    int ph = e + e/10 + e/100;
    float2 z = st[ph];
    float pz = z.x*z.x + z.y*z.y;
    a0 += pz * (float)(e/1000);
    a1 += pz * (float)((e/100)%10);
    a2 += pz * (float)((e/10)%10);
    a3 += pz * (float)(e%10);
  }
  for (int off2 = 32; off2 > 0; off2 >>= 1) {
    a0 += __shfl_down(a0, off2, 64);
    a1 += __shfl_down(a1, off2, 64);
    a2 += __shfl_down(a2, off2, 64);
    a3 += __shfl_down(a3, off2, 64);
  }
  if (lane == 0) {
    redw[wv*4+0] = a0; redw[wv*4+1] = a1;
    redw[wv*4+2] = a2; redw[wv*4+3] = a3;
  }
  __syncthreads();
  if (t < 4) {
    float s = 0.f;
    for (int ww = 0; ww < 16; ++ww) s += redw[ww*4 + t];
    out[b*4 + t] = s;
  }
}

extern "C" void kernel_launch(void* const* d_in, const int* in_sizes, int n_in,
                              void* d_out, int out_size, void* d_ws, size_t ws_size,
                              hipStream_t stream) {
  const void* inp = d_in[0];
  const void* w   = d_in[1];
  float* out = (float*)d_out;                 // reference output dtype is float32
  float2* s0     = (float2*)((char*)d_ws + 16);          // complex S0 (100 float2)
  float*  rslots = (float*)((char*)d_ws + 1024);         // 1968 real 10x10 slots
  float2* lutg   = (float2*)((char*)d_ws + 1024 + NRSLOTS*400);  // 8 x 320 float2

  prep<<<dim3(NRSLOTS + 9), dim3(320), 0, stream>>>(rslots, s0, lutg, inp, w,
                                                    in_sizes[0]);
  expm_all2<<<dim3(NRSLOTS + 1), dim3(128), 0, stream>>>(rslots, s0);
  fused_circuit<<<dim3(NB), dim3(1024), 0, stream>>>(rslots, s0, lutg, out);
}